// Round 1
// baseline (579.544 us; speedup 1.0000x reference)
//
#include <hip/hip_runtime.h>
#include <math.h>

#define NB 2048
#define T 200
#define D 64
#define H1 80
#define H2 40
#define NROWS (NB * T)          // 409600
#define EPSV 1e-8f
#define PADV -4294967295.0f

// workspace layout (float offsets)
#define Z1_OFF   0ull                 // [NROWS][80]  = 32,768,000 floats
#define Z2_OFF   32768000ull          // [NROWS][40]  = 16,384,000 floats
#define RED1_OFF 49152000ull          // sum1[80], sq1[80]
#define FIN1_OFF 49152160ull          // mean1[80], rstd1[80]
#define RED2_OFF 49152320ull          // sum2[40], sq2[40]
#define FIN2_OFF 49152400ull          // mean2[40], rstd2[40]
// total = 49,152,480 floats = ~187.5 MiB

// ---------------------------------------------------------------------------
// K1: z1[b,t,:] = qterm + k @ W_eff     (folded: 4.2 GFLOP instead of 16.8)
//     also accumulates per-h sum / sumsq for dice-1 stats.
// one block per b. 256 threads: 20 h-groups (4h each) x 10 t-groups (4t each)
// ---------------------------------------------------------------------------
__global__ __launch_bounds__(256) void k1_z1(
    const float* __restrict__ qry, const float* __restrict__ keys,
    const float* __restrict__ W1, const float* __restrict__ b1,
    float* __restrict__ z1, float* __restrict__ red1)
{
  const int b = blockIdx.x;
  const int tid = threadIdx.x;
  __shared__ float qsh[D];
  __shared__ float weff[D][H1];      // 20 KB
  __shared__ float qt[H1];
  __shared__ float ksh[40][D + 1];   // 10.4 KB, padded stride 65
  __shared__ float bsum[H1], bsq[H1];

  if (tid < D) qsh[tid] = qry[b * D + tid];
  if (tid < H1) { bsum[tid] = 0.f; bsq[tid] = 0.f; }
  __syncthreads();

  // W_eff[f][h] = W1[64+f][h] - W1[128+f][h] + q[f]*W1[192+f][h]
  for (int idx = tid; idx < D * H1; idx += 256) {
    const int f = idx / H1, h = idx - f * H1;
    weff[f][h] = W1[(64 + f) * H1 + h] - W1[(128 + f) * H1 + h]
               + qsh[f] * W1[(192 + f) * H1 + h];
  }
  // qterm[h] = b1[h] + sum_f q[f]*(W1[f][h] + W1[128+f][h])
  if (tid < H1) {
    float s = b1[tid];
    #pragma unroll 8
    for (int f = 0; f < D; ++f)
      s += qsh[f] * (W1[f * H1 + tid] + W1[(128 + f) * H1 + tid]);
    qt[tid] = s;
  }

  const int hg = tid % 20;           // h-tile index
  const int tq = tid / 20;           // 0..12, active if < 10
  const int h0 = hg * 4;
  float lsum[4] = {0.f, 0.f, 0.f, 0.f};
  float lsq[4]  = {0.f, 0.f, 0.f, 0.f};

  for (int c = 0; c < 5; ++c) {      // t chunks of 40
    const int t0 = c * 40;
    __syncthreads();                 // protect ksh reuse (also covers weff/qt on c==0)
    for (int idx = tid; idx < 40 * D; idx += 256) {
      const int t = idx >> 6, f = idx & 63;
      ksh[t][f] = keys[((size_t)(b * T + t0 + t)) * D + f];
    }
    __syncthreads();
    if (tq < 10) {
      float acc[4][4];
      #pragma unroll
      for (int i = 0; i < 4; ++i)
        #pragma unroll
        for (int j = 0; j < 4; ++j) acc[i][j] = 0.f;
      #pragma unroll 8
      for (int f = 0; f < D; ++f) {
        const float4 w = *(const float4*)&weff[f][h0];
        #pragma unroll
        for (int i = 0; i < 4; ++i) {
          const float kv = ksh[tq * 4 + i][f];
          acc[i][0] = fmaf(kv, w.x, acc[i][0]);
          acc[i][1] = fmaf(kv, w.y, acc[i][1]);
          acc[i][2] = fmaf(kv, w.z, acc[i][2]);
          acc[i][3] = fmaf(kv, w.w, acc[i][3]);
        }
      }
      const float4 qv = *(const float4*)&qt[h0];
      #pragma unroll
      for (int i = 0; i < 4; ++i) {
        const int t = t0 + tq * 4 + i;
        float4 o;
        o.x = acc[i][0] + qv.x; o.y = acc[i][1] + qv.y;
        o.z = acc[i][2] + qv.z; o.w = acc[i][3] + qv.w;
        *(float4*)&z1[((size_t)(b * T + t)) * H1 + h0] = o;
        lsum[0] += o.x; lsq[0] += o.x * o.x;
        lsum[1] += o.y; lsq[1] += o.y * o.y;
        lsum[2] += o.z; lsq[2] += o.z * o.z;
        lsum[3] += o.w; lsq[3] += o.w * o.w;
      }
    }
  }
  __syncthreads();
  if (tq < 10) {
    #pragma unroll
    for (int j = 0; j < 4; ++j) {
      atomicAdd(&bsum[h0 + j], lsum[j]);
      atomicAdd(&bsq[h0 + j], lsq[j]);
    }
  }
  __syncthreads();
  if (tid < H1) {
    atomicAdd(&red1[tid], bsum[tid]);
    atomicAdd(&red1[H1 + tid], bsq[tid]);
  }
}

// ---------------------------------------------------------------------------
// finalize: mean / rstd from sum / sumsq
// ---------------------------------------------------------------------------
__global__ void k_finalize(float* __restrict__ red, float* __restrict__ fin, int H)
{
  const int h = threadIdx.x;
  if (h < H) {
    const float n = (float)NROWS;
    const float mean = red[h] / n;
    const float var = red[H + h] / n - mean * mean;
    fin[h] = mean;
    fin[H + h] = rsqrtf(var + EPSV);
  }
}

// ---------------------------------------------------------------------------
// K3: h1 = dice1(z1); z2 = h1 @ W2 + b2; accumulate dice-2 stats.
// one block per 100 rows. 256 threads: 10 h2-groups (4) x 25 n-groups (4)
// ---------------------------------------------------------------------------
__global__ __launch_bounds__(256) void k3_z2(
    const float* __restrict__ z1, const float* __restrict__ W2,
    const float* __restrict__ b2, const float* __restrict__ a1,
    const float* __restrict__ fin1, float* __restrict__ z2,
    float* __restrict__ red2)
{
  const int r0 = blockIdx.x * 100;
  const int tid = threadIdx.x;
  __shared__ float h1sh[100][H1 + 1];  // 32.4 KB
  __shared__ float w2sh[H1][H2];       // 12.8 KB
  __shared__ float m1[H1], r1[H1], al1[H1];
  __shared__ float b2sh[H2];
  __shared__ float bsum[H2], bsq[H2];

  if (tid < H1) { m1[tid] = fin1[tid]; r1[tid] = fin1[H1 + tid]; al1[tid] = a1[tid]; }
  if (tid < H2) { b2sh[tid] = b2[tid]; bsum[tid] = 0.f; bsq[tid] = 0.f; }
  for (int idx = tid; idx < H1 * H2; idx += 256)
    w2sh[idx / H2][idx - (idx / H2) * H2] = W2[idx];
  __syncthreads();

  for (int idx = tid; idx < 100 * H1; idx += 256) {
    const int n = idx / H1, h = idx - n * H1;
    const float z = z1[((size_t)(r0 + n)) * H1 + h];
    const float xn = (z - m1[h]) * r1[h];
    const float p = 1.f / (1.f + expf(-xn));
    h1sh[n][h] = z * (p + al1[h] * (1.f - p));
  }
  __syncthreads();

  const int hg = tid % 10;      // h2-tile
  const int ng = tid / 10;      // 0..25, active if < 25
  const int h0 = hg * 4;
  if (ng < 25) {
    float acc[4][4];
    #pragma unroll
    for (int i = 0; i < 4; ++i)
      #pragma unroll
      for (int j = 0; j < 4; ++j) acc[i][j] = 0.f;
    #pragma unroll 8
    for (int f = 0; f < H1; ++f) {
      const float4 w = *(const float4*)&w2sh[f][h0];
      #pragma unroll
      for (int i = 0; i < 4; ++i) {
        const float hv = h1sh[ng * 4 + i][f];
        acc[i][0] = fmaf(hv, w.x, acc[i][0]);
        acc[i][1] = fmaf(hv, w.y, acc[i][1]);
        acc[i][2] = fmaf(hv, w.z, acc[i][2]);
        acc[i][3] = fmaf(hv, w.w, acc[i][3]);
      }
    }
    float lsum[4] = {0.f,0.f,0.f,0.f}, lsq[4] = {0.f,0.f,0.f,0.f};
    #pragma unroll
    for (int i = 0; i < 4; ++i) {
      const int n = ng * 4 + i;
      float4 o;
      o.x = acc[i][0] + b2sh[h0 + 0];
      o.y = acc[i][1] + b2sh[h0 + 1];
      o.z = acc[i][2] + b2sh[h0 + 2];
      o.w = acc[i][3] + b2sh[h0 + 3];
      *(float4*)&z2[((size_t)(r0 + n)) * H2 + h0] = o;
      lsum[0] += o.x; lsq[0] += o.x * o.x;
      lsum[1] += o.y; lsq[1] += o.y * o.y;
      lsum[2] += o.z; lsq[2] += o.z * o.z;
      lsum[3] += o.w; lsq[3] += o.w * o.w;
    }
    #pragma unroll
    for (int j = 0; j < 4; ++j) {
      atomicAdd(&bsum[h0 + j], lsum[j]);
      atomicAdd(&bsq[h0 + j], lsq[j]);
    }
  }
  __syncthreads();
  if (tid < H2) {
    atomicAdd(&red2[tid], bsum[tid]);
    atomicAdd(&red2[H2 + tid], bsq[tid]);
  }
}

// ---------------------------------------------------------------------------
// K5: h2 = dice2(z2); scores = h2@W3+b3; mask; softmax over T; out = w @ keys
// one block per b, 256 threads.
// ---------------------------------------------------------------------------
__global__ __launch_bounds__(256) void k5_out(
    const float* __restrict__ z2, const float* __restrict__ keys,
    const int* __restrict__ mask, const float* __restrict__ a2,
    const float* __restrict__ fin2, const float* __restrict__ W3,
    const float* __restrict__ b3, float* __restrict__ out)
{
  const int b = blockIdx.x;
  const int tid = threadIdx.x;
  __shared__ float h2sh[T][H2 + 1];    // 32.8 KB
  __shared__ float w3sh[H2], m2[H2], r2[H2], al2[H2];
  __shared__ float ssh[256];
  __shared__ float red[8];
  __shared__ float osh[4][D];

  if (tid < H2) {
    w3sh[tid] = W3[tid];
    m2[tid] = fin2[tid];
    r2[tid] = fin2[H2 + tid];
    al2[tid] = a2[tid];
  }
  __syncthreads();
  for (int idx = tid; idx < T * H2; idx += 256) {
    const int t = idx / H2, h = idx - t * H2;
    const float z = z2[((size_t)(b * T + t)) * H2 + h];
    const float xn = (z - m2[h]) * r2[h];
    const float p = 1.f / (1.f + expf(-xn));
    h2sh[t][h] = z * (p + al2[h] * (1.f - p));
  }
  __syncthreads();

  float s;
  if (tid < T) {
    s = b3[0];
    #pragma unroll 8
    for (int f = 0; f < H2; ++f) s = fmaf(h2sh[tid][f], w3sh[f], s);
    s = mask[b * T + tid] ? s : PADV;
  } else {
    s = -INFINITY;
  }
  // block max
  float v = s;
  #pragma unroll
  for (int o = 32; o > 0; o >>= 1) v = fmaxf(v, __shfl_xor(v, o, 64));
  const int wid = tid >> 6, lane = tid & 63;
  if (lane == 0) red[wid] = v;
  __syncthreads();
  const float m = fmaxf(fmaxf(red[0], red[1]), fmaxf(red[2], red[3]));
  const float e = (tid < T) ? expf(s - m) : 0.f;
  ssh[tid] = e;
  float v2 = e;
  #pragma unroll
  for (int o = 32; o > 0; o >>= 1) v2 += __shfl_xor(v2, o, 64);
  if (lane == 0) red[4 + wid] = v2;
  __syncthreads();                      // covers ssh writes too
  const float inv = 1.f / (red[4] + red[5] + red[6] + red[7]);

  // out[b,d] = sum_t w[t] * keys[b,t,d]
  const int dd = tid & 63, tg = tid >> 6;
  float p = 0.f;
  for (int t = tg; t < T; t += 4)
    p = fmaf(ssh[t], keys[((size_t)(b * T + t)) * D + dd], p);
  osh[tg][dd] = p * inv;
  __syncthreads();
  if (tid < D)
    out[(size_t)b * D + tid] = osh[0][tid] + osh[1][tid] + osh[2][tid] + osh[3][tid];
}

// ---------------------------------------------------------------------------
extern "C" void kernel_launch(void* const* d_in, const int* in_sizes, int n_in,
                              void* d_out, int out_size, void* d_ws, size_t ws_size,
                              hipStream_t stream)
{
  const float* qry  = (const float*)d_in[0];
  const float* keys = (const float*)d_in[1];
  const int*   mask = (const int*)d_in[2];
  const float* W1   = (const float*)d_in[3];
  const float* b1   = (const float*)d_in[4];
  const float* a1   = (const float*)d_in[5];
  const float* W2   = (const float*)d_in[6];
  const float* b2   = (const float*)d_in[7];
  const float* a2   = (const float*)d_in[8];
  const float* W3   = (const float*)d_in[9];
  const float* b3   = (const float*)d_in[10];
  float* out = (float*)d_out;
  float* ws  = (float*)d_ws;

  float* z1   = ws + Z1_OFF;
  float* z2   = ws + Z2_OFF;
  float* red1 = ws + RED1_OFF;
  float* fin1 = ws + FIN1_OFF;
  float* red2 = ws + RED2_OFF;
  float* fin2 = ws + FIN2_OFF;

  // zero the stat accumulators (480 floats, contiguous)
  hipMemsetAsync(red1, 0, 480 * sizeof(float), stream);

  k1_z1<<<NB, 256, 0, stream>>>(qry, keys, W1, b1, z1, red1);
  k_finalize<<<1, 128, 0, stream>>>(red1, fin1, H1);
  k3_z2<<<NROWS / 100, 256, 0, stream>>>(z1, W2, b2, a1, fin1, z2, red2);
  k_finalize<<<1, 128, 0, stream>>>(red2, fin2, H2);
  k5_out<<<NB, 256, 0, stream>>>(z2, keys, mask, a2, fin2, W3, b3, out);
}